// Round 12
// baseline (214.897 us; speedup 1.0000x reference)
//
#include <hip/hip_runtime.h>
#include <hip/hip_bf16.h>

typedef unsigned int uint;
typedef unsigned short u16;

// Dims fixed by the problem
#define DIN 128
#define DHID 128
#define DOUT 64
#define BSH 8          // bucket = dst >> 8 (256 nodes per bucket)
#define P3CHUNK 4096   // edges per partition block (R11: halved to shorten serial path)
#define P4MAX 6144     // LDS staging cap per bucket in emit

static inline size_t al256(size_t x) { return (x + 255) & ~(size_t)255; }

typedef __attribute__((ext_vector_type(8))) short short8;
typedef __attribute__((ext_vector_type(4))) float floatx4;
typedef __attribute__((ext_vector_type(2))) float floatx2;
typedef __attribute__((ext_vector_type(4))) int intx4;   // clang vector for nontemporal builtins

// bf16 pair helpers (uint = two bf16, low bits = even feature)
__device__ inline float2 bf2x(uint v) {
    return make_float2(__uint_as_float(v << 16), __uint_as_float(v & 0xffff0000u));
}
__device__ inline uint packbf(float a, float b) {
    uint ua = __float_as_uint(a), ub = __float_as_uint(b);
    ua += 0x7fff + ((ua >> 16) & 1);   // RNE
    ub += 0x7fff + ((ub >> 16) & 1);
    return (ua >> 16) | (ub & 0xffff0000u);
}
__device__ inline u16 pb(float a) {
    uint u = __float_as_uint(a);
    u += 0x7fff + ((u >> 16) & 1);
    return (u16)(u >> 16);
}

// ---- fp8 e4m3 helpers (HW cvt if available, exact software fallback) ----
__device__ inline floatx2 f8lo(uint v) {
#if __has_builtin(__builtin_amdgcn_cvt_pk_f32_fp8)
    return __builtin_amdgcn_cvt_pk_f32_fp8((int)v, false);
#else
    uint b0 = v & 0xffu, b1 = (v >> 8) & 0xffu;
    floatx2 r;
    r.x = __uint_as_float(((b0 & 0x80u) << 24) | ((b0 & 0x7fu) << 20)) * 0x1p120f;
    r.y = __uint_as_float(((b1 & 0x80u) << 24) | ((b1 & 0x7fu) << 20)) * 0x1p120f;
    return r;
#endif
}
__device__ inline floatx2 f8hi(uint v) {
#if __has_builtin(__builtin_amdgcn_cvt_pk_f32_fp8)
    return __builtin_amdgcn_cvt_pk_f32_fp8((int)v, true);
#else
    uint b0 = (v >> 16) & 0xffu, b1 = (v >> 24) & 0xffu;
    floatx2 r;
    r.x = __uint_as_float(((b0 & 0x80u) << 24) | ((b0 & 0x7fu) << 20)) * 0x1p120f;
    r.y = __uint_as_float(((b1 & 0x80u) << 24) | ((b1 & 0x7fu) << 20)) * 0x1p120f;
    return r;
#endif
}
__device__ inline uint enc8(float f) {
    uint ub = __float_as_uint(f * 0x1p-120f);
    uint s = (ub >> 24) & 0x80u;
    uint mag = ub & 0x7fffffffu;
    mag += 0x7ffffu + ((mag >> 20) & 1u);
    uint r = mag >> 20;
    if (r > 0x7eu) r = 0x7eu;
    return r | s;
}
__device__ inline uint packf8x4(float a, float b, float c, float d) {
#if __has_builtin(__builtin_amdgcn_cvt_pk_fp8_f32)
    int p = __builtin_amdgcn_cvt_pk_fp8_f32(a, b, 0, false);
    p = __builtin_amdgcn_cvt_pk_fp8_f32(c, d, p, true);
    return (uint)p;
#else
    return enc8(a) | (enc8(b) << 8) | (enc8(c) << 16) | (enc8(d) << 24);
#endif
}

// ---- pack W (blocks 0..191) + mask detect (192..255) + bucket hist (256..511) ----
__global__ __launch_bounds__(256) void pack_detect_bhist_kernel(
    const float* __restrict__ W1l, const float* __restrict__ W1r,
    const float* __restrict__ W2l, const float* __restrict__ W2r,
    u16* __restrict__ Wp1, u16* __restrict__ Wp2,
    const int* __restrict__ tm, int n_int, int* __restrict__ gflags,
    const int* __restrict__ dst, int e, int nb, uint* __restrict__ bcounts) {
    __shared__ uint lh[512];
    int bx = blockIdx.x;
    if (bx < 192) {
        int id = bx * 256 + threadIdx.x;
        if (id < 32768) {
            int frag = id >> 9, el = id & 511;
            int lane = el >> 3, j = el & 7;
            int kc = frag >> 4, tn = frag & 15;
            int k = kc * 32 + (lane >> 4) * 8 + j;
            int ncol = tn * 16 + (lane & 15);
            float v = (ncol < 128) ? W1l[k * 128 + ncol] : W1r[k * 128 + ncol - 128];
            Wp1[id] = pb(v);
        } else if (id < 49152) {
            int id2 = id - 32768;
            int frag = id2 >> 9, el = id2 & 511;
            int lane = el >> 3, j = el & 7;
            int kc = frag >> 3, tn = frag & 7;
            int k = kc * 32 + (lane >> 4) * 8 + j;
            int ncol = tn * 16 + (lane & 15);
            float v = (ncol < 64) ? W2l[k * 64 + ncol] : W2r[k * 64 + ncol - 64];
            Wp2[id2] = pb(v);
        }
    } else if (bx < 256) {
        int i = (bx - 192) * 256 + threadIdx.x;
        bool hf = false, ho = false;
        for (; i < n_int; i += 64 * 256) {
            int v = tm[i];
            hf |= (v == 0x3F800000);
            ho |= (v != 0 && v != 1 && v != 0x3F800000);
        }
        if (__any(hf) && (threadIdx.x & 63) == 0) atomicOr(&gflags[0], 1);
        if (__any(ho) && (threadIdx.x & 63) == 0) atomicOr(&gflags[1], 1);
    } else {
        for (int i = threadIdx.x; i < 512; i += 256) lh[i] = 0;
        __syncthreads();
        int nquad = (e + 3) >> 2;
        for (int i = (bx - 256) * 256 + threadIdx.x; i < nquad; i += 256 * 256) {
            int base = i * 4;
            if (base + 4 <= e) {
                intx4 d = __builtin_nontemporal_load((const intx4*)(dst + base));
                atomicAdd(&lh[d.x >> BSH], 1u);
                atomicAdd(&lh[d.y >> BSH], 1u);
                atomicAdd(&lh[d.z >> BSH], 1u);
                atomicAdd(&lh[d.w >> BSH], 1u);
            } else {
                for (int k = base; k < e; ++k) atomicAdd(&lh[dst[k] >> BSH], 1u);
            }
        }
        __syncthreads();
        for (int i = threadIdx.x; i < nb; i += 256) {
            uint c = lh[i];
            if (c) atomicAdd(&bcounts[i], c);
        }
    }
}

// ---- fused: blocks [0, npart) = partition; blocks [npart, ...) = gemm1 MFMA ----
// Partition path LDS: 2056 + P3CHUNK = 6152 uints (24.6 KB); gemm1 path: 33.3 KB -> 4 blocks/CU.
__global__ __launch_bounds__(256) void partition_gemm1_kernel(
    const int* __restrict__ src, const int* __restrict__ dst, int e, int nb,
    const uint* __restrict__ bcounts, uint* __restrict__ bcursor,
    uint* __restrict__ pairs, int npart,
    const float* __restrict__ X, const u16* __restrict__ Wp1,
    const float* __restrict__ b1,
    uint* __restrict__ P1f8, uint* __restrict__ Q1u, int n) {
    __shared__ uint sbuf[8320];   // 33,280 B, aliased by both paths
    int t = threadIdx.x;
    if (blockIdx.x < npart) {
        uint* lh    = sbuf;          // 512
        uint* lexcl = sbuf + 512;    // 512
        uint* lbase = sbuf + 1024;   // 512
        uint* lpos  = sbuf + 1536;   // 512
        uint* pws   = sbuf + 2048;   // 8
        uint* st    = sbuf + 2056;   // P3CHUNK (4096)
        int e0 = blockIdx.x * P3CHUNK;
        int ecnt = min(P3CHUNK, e - e0);
        for (int i = t; i < 512; i += 256) { lh[i] = 0; lpos[i] = 0; }
        __syncthreads();
        // Phase A: local bucket histogram (4 edges/thread, vectorized)
        int nquad = (ecnt + 3) >> 2;
        for (int i = t; i < nquad; i += 256) {
            int b4 = i * 4;
            if (b4 + 4 <= ecnt) {
                intx4 d = *(const intx4*)(dst + e0 + b4);
                atomicAdd(&lh[d.x >> BSH], 1u);
                atomicAdd(&lh[d.y >> BSH], 1u);
                atomicAdd(&lh[d.z >> BSH], 1u);
                atomicAdd(&lh[d.w >> BSH], 1u);
            } else {
                for (int k = b4; k < ecnt; ++k) atomicAdd(&lh[dst[e0 + k] >> BSH], 1u);
            }
        }
        __syncthreads();
        // Phase B1: chunk-local exclusive scan of lh -> lexcl
        {
            uint v0 = lh[2 * t], v1 = lh[2 * t + 1];
            uint s = v0 + v1;
            int lane = t & 63, wv = t >> 6;
            uint incl = s;
            #pragma unroll
            for (int d = 1; d < 64; d <<= 1) {
                uint u = (uint)__shfl_up((int)incl, d, 64);
                if (lane >= d) incl += u;
            }
            if (lane == 63) pws[wv] = incl;
            __syncthreads();
            uint woff = 0;
            #pragma unroll
            for (int i = 0; i < 4; ++i) if (i < wv) woff += pws[i];
            uint excl = woff + incl - s;
            lexcl[2 * t] = excl;
            lexcl[2 * t + 1] = excl + v0;
        }
        __syncthreads();
        // Phase B2: global bucket-base scan of bcounts -> lbase
        {
            uint v0 = (2 * t < nb) ? bcounts[2 * t] : 0u;
            uint v1 = (2 * t + 1 < nb) ? bcounts[2 * t + 1] : 0u;
            uint s = v0 + v1;
            int lane = t & 63, wv = t >> 6;
            uint incl = s;
            #pragma unroll
            for (int d = 1; d < 64; d <<= 1) {
                uint u = (uint)__shfl_up((int)incl, d, 64);
                if (lane >= d) incl += u;
            }
            if (lane == 63) pws[wv] = incl;
            __syncthreads();
            uint woff = 0;
            #pragma unroll
            for (int i = 0; i < 4; ++i) if (i < wv) woff += pws[i];
            uint excl = woff + incl - s;
            if (2 * t < nb) lbase[2 * t] = excl;
            if (2 * t + 1 < nb) lbase[2 * t + 1] = excl + v0;
        }
        __syncthreads();
        // claim global space per non-empty bucket (bcursor zero-initialized)
        for (int b = t; b < nb; b += 256) {
            uint c = lh[b];
            if (c) lbase[b] += atomicAdd(&bcursor[b], c);
        }
        __syncthreads();
        // Phase C: scatter pairs into LDS grouped by bucket (vectorized reads)
        for (int i = t; i < nquad; i += 256) {
            int b4 = i * 4;
            if (b4 + 4 <= ecnt) {
                intx4 dd = *(const intx4*)(dst + e0 + b4);
                intx4 ss = *(const intx4*)(src + e0 + b4);
                #pragma unroll
                for (int k = 0; k < 4; ++k) {
                    int d = (k == 0) ? dd.x : (k == 1) ? dd.y : (k == 2) ? dd.z : dd.w;
                    int s = (k == 0) ? ss.x : (k == 1) ? ss.y : (k == 2) ? ss.z : ss.w;
                    int b = d >> BSH;
                    uint slot = lexcl[b] + atomicAdd(&lpos[b], 1u);
                    st[slot] = ((uint)(d & ((1 << BSH) - 1)) << 16) | (uint)s;
                }
            } else {
                for (int k = b4; k < ecnt; ++k) {
                    int d = dst[e0 + k];
                    int s = src[e0 + k];
                    int b = d >> BSH;
                    uint slot = lexcl[b] + atomicAdd(&lpos[b], 1u);
                    st[slot] = ((uint)(d & ((1 << BSH) - 1)) << 16) | (uint)s;
                }
            }
        }
        __syncthreads();
        // Phase D: coalesced copy of each bucket run to global
        int wv = t >> 6, lane = t & 63;
        for (int b = wv; b < nb; b += 4) {
            uint c = lh[b];
            uint lsrc = lexcl[b], gdst = lbase[b];
            for (uint k = lane; k < c; k += 64)
                pairs[gdst + k] = st[lsrc + k];
        }
        return;
    }
    // ---------- gemm1: 32 rows/wave ----------
    u16* ep = (u16*)sbuf;   // [4][16][260]
    int bid = blockIdx.x - npart;
    int w = t >> 6, lane = t & 63;
    int q = lane >> 4, c = lane & 15;
    int m0 = bid * 128 + w * 32;
    int meA = min(m0 + c, n - 1);
    int meB = min(m0 + 16 + c, n - 1);
    const float* xrowA = X + (size_t)meA * 128 + q * 8;
    const float* xrowB = X + (size_t)meB * 128 + q * 8;
    const u16* wbase = Wp1 + lane * 8;

    floatx4 acc[2][16];
    #pragma unroll
    for (int h = 0; h < 2; ++h)
        #pragma unroll
        for (int i = 0; i < 16; ++i) acc[h][i] = (floatx4){0.f, 0.f, 0.f, 0.f};

    #pragma unroll
    for (int kc = 0; kc < 4; ++kc) {
        float4 xa0 = *(const float4*)(xrowA + kc * 32);
        float4 xa1 = *(const float4*)(xrowA + kc * 32 + 4);
        float4 xb0 = *(const float4*)(xrowB + kc * 32);
        float4 xb1 = *(const float4*)(xrowB + kc * 32 + 4);
        union { short8 s; uint4 u; } a0, a1;
        a0.u.x = packbf(xa0.x, xa0.y); a0.u.y = packbf(xa0.z, xa0.w);
        a0.u.z = packbf(xa1.x, xa1.y); a0.u.w = packbf(xa1.z, xa1.w);
        a1.u.x = packbf(xb0.x, xb0.y); a1.u.y = packbf(xb0.z, xb0.w);
        a1.u.z = packbf(xb1.x, xb1.y); a1.u.w = packbf(xb1.z, xb1.w);
        #pragma unroll
        for (int tn = 0; tn < 16; ++tn) {
            union { short8 s; uint4 u; } b;
            b.u = *(const uint4*)(wbase + (kc * 16 + tn) * 512);
            acc[0][tn] = __builtin_amdgcn_mfma_f32_16x16x32_bf16(a0.s, b.s, acc[0][tn], 0, 0, 0);
            acc[1][tn] = __builtin_amdgcn_mfma_f32_16x16x32_bf16(a1.s, b.s, acc[1][tn], 0, 0, 0);
        }
    }

    #pragma unroll
    for (int h = 0; h < 2; ++h) {
        #pragma unroll
        for (int tn = 0; tn < 16; ++tn) {
            int col = tn * 16 + c;
            float badd = (tn >= 8) ? b1[col - 128] : 0.f;
            #pragma unroll
            for (int i = 0; i < 4; ++i)
                ep[((size_t)w * 16 + (q * 4 + i)) * 260 + col] = pb(acc[h][tn][i] + badd);
        }
        int r0 = m0 + h * 16;
        for (int r = 0; r < 16; ++r) {
            int grow = r0 + r;
            if (grow >= n) continue;
            uint2 v = *(const uint2*)&ep[((size_t)w * 16 + r) * 260 + lane * 4];
            if (lane < 32) {
                float2 e0 = bf2x(v.x), e1 = bf2x(v.y);
                P1f8[(size_t)grow * 32 + lane] = packf8x4(e0.x, e0.y, e1.x, e1.y);
            } else {
                *(uint2*)&Q1u[(size_t)grow * 64 + 2 * (lane - 32)] = v;
            }
        }
    }
}

// emit: per-bucket local sort -> dense csr segment + offsets (computes bucket bases locally)
__global__ __launch_bounds__(256) void emit_kernel(const uint* __restrict__ pairs,
                                                   const uint* __restrict__ bcounts, int nb,
                                                   int e, int n,
                                                   u16* __restrict__ csr, int* __restrict__ offsets) {
    __shared__ uint cnt[256], lex[256], gb[512], pws[8];
    __shared__ u16 ob[P4MAX];
    int b = blockIdx.x, t = threadIdx.x;
    {
        uint v0 = (2 * t < nb) ? bcounts[2 * t] : 0u;
        uint v1 = (2 * t + 1 < nb) ? bcounts[2 * t + 1] : 0u;
        uint s = v0 + v1;
        int lane = t & 63, wv = t >> 6;
        uint incl = s;
        #pragma unroll
        for (int d = 1; d < 64; d <<= 1) {
            uint u = (uint)__shfl_up((int)incl, d, 64);
            if (lane >= d) incl += u;
        }
        if (lane == 63) pws[wv] = incl;
        __syncthreads();
        uint woff = 0;
        #pragma unroll
        for (int i = 0; i < 4; ++i) if (i < wv) woff += pws[i];
        uint excl = woff + incl - s;
        if (2 * t < nb) gb[2 * t] = excl;
        if (2 * t + 1 < nb) gb[2 * t + 1] = excl + v0;
    }
    __syncthreads();
    uint seg0 = gb[b];
    int len = (int)bcounts[b];
    int n0 = b << BSH;
    if (b == 0 && t == 0) offsets[n] = e;
    cnt[t] = 0;
    __syncthreads();
    for (int i = t; i < len; i += 256)
        atomicAdd(&cnt[pairs[seg0 + i] >> 16], 1u);
    __syncthreads();
    uint v = cnt[t];
    int lane = t & 63, wv = t >> 6;
    uint incl = v;
    #pragma unroll
    for (int d = 1; d < 64; d <<= 1) {
        uint u = (uint)__shfl_up((int)incl, d, 64);
        if (lane >= d) incl += u;
    }
    if (lane == 63) pws[wv] = incl;
    __syncthreads();
    uint woff = 0;
    #pragma unroll
    for (int i = 0; i < 4; ++i) if (i < wv) woff += pws[i];
    uint excl = woff + incl - v;
    lex[t] = excl;
    if (n0 + t < n) offsets[n0 + t] = (int)(seg0 + excl);
    __syncthreads();
    cnt[t] = 0;
    __syncthreads();
    for (int i = t; i < len; i += 256) {
        uint p = pairs[seg0 + i];
        uint loc = p >> 16;
        uint slot = lex[loc] + atomicAdd(&cnt[loc], 1u);
        if (slot < P4MAX) ob[slot] = (u16)(p & 0xffffu);
        else csr[seg0 + slot] = (u16)(p & 0xffffu);
    }
    __syncthreads();
    int lim = min(len, P4MAX);
    for (int i = t; i < lim; i += 256) csr[seg0 + i] = ob[i];
}

// ================= fallback CSR build for N > 65535 (old path) =================
__global__ __launch_bounds__(256) void hist_kernel(const int* __restrict__ dst, int e,
                                                   int* __restrict__ counts) {
    int base = (blockIdx.x * 256 + threadIdx.x) * 4;
    if (base + 4 <= e) {
        intx4 d = __builtin_nontemporal_load((const intx4*)(dst + base));
        atomicAdd(&counts[d.x], 1);
        atomicAdd(&counts[d.y], 1);
        atomicAdd(&counts[d.z], 1);
        atomicAdd(&counts[d.w], 1);
    } else {
        for (int i = base; i < e; ++i) atomicAdd(&counts[dst[i]], 1);
    }
}

__global__ __launch_bounds__(256) void scan_partial_kernel(const int* __restrict__ counts, int n,
                                                           int* __restrict__ partials) {
    int t = threadIdx.x;
    int base = blockIdx.x * 1024 + t * 4;
    int s = 0;
    if (base + 3 < n) {
        int4 v = *(const int4*)&counts[base];
        s = v.x + v.y + v.z + v.w;
    } else {
        for (int i = 0; i < 4; ++i) if (base + i < n) s += counts[base + i];
    }
    #pragma unroll
    for (int d = 32; d; d >>= 1) s += __shfl_down(s, d, 64);
    __shared__ int wsum[4];
    if ((t & 63) == 0) wsum[t >> 6] = s;
    __syncthreads();
    if (t == 0) partials[blockIdx.x] = wsum[0] + wsum[1] + wsum[2] + wsum[3];
}

__global__ void scan_top_kernel(int* __restrict__ partials, int nparts, int* __restrict__ total_out) {
    int lane = threadIdx.x;
    int v = (lane < nparts) ? partials[lane] : 0;
    int incl = v;
    #pragma unroll
    for (int d = 1; d < 64; d <<= 1) {
        int u = __shfl_up(incl, d, 64);
        if (lane >= d) incl += u;
    }
    if (lane < nparts) partials[lane] = incl - v;
    if (lane == 63) *total_out = incl;
}

__global__ __launch_bounds__(256) void scan_final_kernel(const int* __restrict__ counts, int n,
                                                         const int* __restrict__ partials,
                                                         int* __restrict__ offsets,
                                                         int* __restrict__ cursor) {
    int t = threadIdx.x;
    int base = blockIdx.x * 1024 + t * 4;
    int v0 = 0, v1 = 0, v2 = 0, v3 = 0;
    if (base + 3 < n) {
        int4 q = *(const int4*)&counts[base];
        v0 = q.x; v1 = q.y; v2 = q.z; v3 = q.w;
    } else {
        if (base + 0 < n) v0 = counts[base + 0];
        if (base + 1 < n) v1 = counts[base + 1];
        if (base + 2 < n) v2 = counts[base + 2];
        if (base + 3 < n) v3 = counts[base + 3];
    }
    int s = v0 + v1 + v2 + v3;
    int lane = t & 63, wid = t >> 6;
    int incl = s;
    #pragma unroll
    for (int d = 1; d < 64; d <<= 1) {
        int u = __shfl_up(incl, d, 64);
        if (lane >= d) incl += u;
    }
    __shared__ int wsum[4];
    if (lane == 63) wsum[wid] = incl;
    __syncthreads();
    int woff = 0;
    #pragma unroll
    for (int i = 0; i < 4; ++i) if (i < wid) woff += wsum[i];
    int run = partials[blockIdx.x] + woff + incl - s;
    if (base + 0 < n) { offsets[base + 0] = run; cursor[base + 0] = run; run += v0; }
    if (base + 1 < n) { offsets[base + 1] = run; cursor[base + 1] = run; run += v1; }
    if (base + 2 < n) { offsets[base + 2] = run; cursor[base + 2] = run; run += v2; }
    if (base + 3 < n) { offsets[base + 3] = run; cursor[base + 3] = run; run += v3; }
}

__global__ __launch_bounds__(256) void scatter_kernel(const int* __restrict__ src,
                                                      const int* __restrict__ dst, int e,
                                                      int* __restrict__ cursor,
                                                      uint* __restrict__ csr_src) {
    int base = (blockIdx.x * 256 + threadIdx.x) * 4;
    if (base + 4 <= e) {
        intx4 s = __builtin_nontemporal_load((const intx4*)(src + base));
        intx4 d = __builtin_nontemporal_load((const intx4*)(dst + base));
        int p0 = atomicAdd(&cursor[d.x], 1);
        int p1 = atomicAdd(&cursor[d.y], 1);
        int p2 = atomicAdd(&cursor[d.z], 1);
        int p3 = atomicAdd(&cursor[d.w], 1);
        csr_src[p0] = (uint)s.x;
        csr_src[p1] = (uint)s.y;
        csr_src[p2] = (uint)s.z;
        csr_src[p3] = (uint)s.w;
    } else {
        for (int i = base; i < e; ++i) {
            int p = atomicAdd(&cursor[dst[i]], 1);
            csr_src[p] = (uint)src[i];
        }
    }
}

// ---------------- aggr1: h1 = bf16(relu(mean(P1) + Q1)), half-wave per edge ----------------
template <typename IT>
__global__ __launch_bounds__(256) void aggr1_kernel(
    const uint* __restrict__ P1f8, const uint* __restrict__ Q1u,
    const int* __restrict__ offsets, const IT* __restrict__ csr,
    uint* __restrict__ h1u, int n) {
    int node = (int)((blockIdx.x * (size_t)blockDim.x + threadIdx.x) >> 6);
    int lane = threadIdx.x & 63;
    int l = lane & 31, hw = lane >> 5;
    if (node >= n) return;
    int beg = offsets[node], end = offsets[node + 1];
    float a0 = 0.f, a1 = 0.f, a2 = 0.f, a3 = 0.f;
    int i = beg + hw;
    for (; i + 6 < end; i += 8) {
        int s0 = csr[i], s1 = csr[i + 2], s2 = csr[i + 4], s3 = csr[i + 6];
        uint v0 = P1f8[(size_t)s0 * 32 + l];
        uint v1 = P1f8[(size_t)s1 * 32 + l];
        uint v2 = P1f8[(size_t)s2 * 32 + l];
        uint v3 = P1f8[(size_t)s3 * 32 + l];
        floatx2 u0 = f8lo(v0), w0 = f8hi(v0);
        floatx2 u1 = f8lo(v1), w1 = f8hi(v1);
        floatx2 u2 = f8lo(v2), w2 = f8hi(v2);
        floatx2 u3 = f8lo(v3), w3 = f8hi(v3);
        a0 += (u0.x + u1.x) + (u2.x + u3.x);
        a1 += (u0.y + u1.y) + (u2.y + u3.y);
        a2 += (w0.x + w1.x) + (w2.x + w3.x);
        a3 += (w0.y + w1.y) + (w2.y + w3.y);
    }
    for (; i < end; i += 2) {
        int s = csr[i];
        uint v = P1f8[(size_t)s * 32 + l];
        floatx2 u = f8lo(v), w2 = f8hi(v);
        a0 += u.x; a1 += u.y; a2 += w2.x; a3 += w2.y;
    }
    a0 += __shfl_xor(a0, 32, 64);
    a1 += __shfl_xor(a1, 32, 64);
    a2 += __shfl_xor(a2, 32, 64);
    a3 += __shfl_xor(a3, 32, 64);
    if (hw == 0) {
        float inv = 1.0f / (float)max(end - beg, 1);
        uint2 qv = *(const uint2*)&Q1u[(size_t)node * 64 + l * 2];
        float2 q0 = bf2x(qv.x), q1 = bf2x(qv.y);
        float r0 = fmaxf(fmaf(a0, inv, q0.x), 0.f);
        float r1 = fmaxf(fmaf(a1, inv, q0.y), 0.f);
        float r2 = fmaxf(fmaf(a2, inv, q1.x), 0.f);
        float r3 = fmaxf(fmaf(a3, inv, q1.y), 0.f);
        uint2 o;
        o.x = packbf(r0, r1);
        o.y = packbf(r2, r3);
        *(uint2*)&h1u[(size_t)node * 64 + l * 2] = o;
    }
}

// ---------------- gemm2 (MFMA): 32 rows/wave; P2 = fp8(h1@W2l), Q2 = bf16(h1@W2r + b2) ----------------
__global__ __launch_bounds__(256) void gemm2_mfma(
    const uint* __restrict__ H1u, const u16* __restrict__ Wp2,
    const float* __restrict__ b2,
    uint* __restrict__ P2f8, uint* __restrict__ Q2u, int n) {
    __shared__ u16 ep[4][16][132];
    int t = threadIdx.x;
    int w = t >> 6, lane = t & 63;
    int q = lane >> 4, c = lane & 15;
    int m0 = blockIdx.x * 128 + w * 32;
    int meA = min(m0 + c, n - 1);
    int meB = min(m0 + 16 + c, n - 1);
    const u16* hrowA = (const u16*)H1u + (size_t)meA * 128 + q * 8;
    const u16* hrowB = (const u16*)H1u + (size_t)meB * 128 + q * 8;
    const u16* wbase = Wp2 + lane * 8;

    floatx4 acc[2][8];
    #pragma unroll
    for (int h = 0; h < 2; ++h)
        #pragma unroll
        for (int i = 0; i < 8; ++i) acc[h][i] = (floatx4){0.f, 0.f, 0.f, 0.f};

    #pragma unroll
    for (int kc = 0; kc < 4; ++kc) {
        union { short8 s; uint4 u; } a0, a1;
        a0.u = *(const uint4*)(hrowA + kc * 32);
        a1.u = *(const uint4*)(hrowB + kc * 32);
        #pragma unroll
        for (int tn = 0; tn < 8; ++tn) {
            union { short8 s; uint4 u; } b;
            b.u = *(const uint4*)(wbase + (kc * 8 + tn) * 512);
            acc[0][tn] = __builtin_amdgcn_mfma_f32_16x16x32_bf16(a0.s, b.s, acc[0][tn], 0, 0, 0);
            acc[1][tn] = __builtin_amdgcn_mfma_f32_16x16x32_bf16(a1.s, b.s, acc[1][tn], 0, 0, 0);
        }
    }

    #pragma unroll
    for (int h = 0; h < 2; ++h) {
        #pragma unroll
        for (int tn = 0; tn < 8; ++tn) {
            int col = tn * 16 + c;
            float badd = (tn >= 4) ? b2[col - 64] : 0.f;
            #pragma unroll
            for (int i = 0; i < 4; ++i)
                ep[w][q * 4 + i][col] = pb(acc[h][tn][i] + badd);
        }
        int r0 = m0 + h * 16;
        for (int r = 0; r < 16; ++r) {
            int grow = r0 + r;
            if (grow >= n) continue;
            if (lane < 16) {
                uint2 v = *(const uint2*)&ep[w][r][lane * 4];
                float2 e0 = bf2x(v.x), e1 = bf2x(v.y);
                P2f8[(size_t)grow * 16 + lane] = packf8x4(e0.x, e0.y, e1.x, e1.y);
            } else if (lane < 48) {
                uint v = *(const uint*)&ep[w][r][64 + (lane - 16) * 2];
                Q2u[(size_t)grow * 32 + (lane - 16)] = v;
            }
        }
    }
}

// ---------------- loss: logits = mean(P2) + Q2 ; log_softmax ; masked NLL ----------------
// Per-block float2 partial (NO global atomics / fences — R8's fused finalize cost ~100 µs).
template <typename IT>
__global__ __launch_bounds__(1024) void loss_kernel(
    const uint* __restrict__ P2f8, const uint* __restrict__ Q2u,
    const int* __restrict__ offsets, const IT* __restrict__ csr,
    const int* __restrict__ y, const void* __restrict__ tmask,
    const int* __restrict__ gflags, float2* __restrict__ bpart, int n) {
    __shared__ int sflag;
    if (threadIdx.x == 0) sflag = gflags[0] ? 2 : (gflags[1] ? 0 : 1);
    int wid = threadIdx.x >> 6;
    int node = blockIdx.x * 16 + wid;
    int lane = threadIdx.x & 63;
    int l = lane & 15, qw = lane >> 4;
    __syncthreads();
    float num = 0.f, den = 0.f;
    if (node < n) {
        int beg = offsets[node], end = offsets[node + 1];
        float a0 = 0.f, a1 = 0.f, a2 = 0.f, a3 = 0.f;
        int i = beg + qw;
        for (; i + 4 < end; i += 8) {
            int s0 = csr[i], s1 = csr[i + 4];
            uint v0 = P2f8[(size_t)s0 * 16 + l];
            uint v1 = P2f8[(size_t)s1 * 16 + l];
            floatx2 u0 = f8lo(v0), w0 = f8hi(v0);
            floatx2 u1 = f8lo(v1), w1 = f8hi(v1);
            a0 += u0.x + u1.x; a1 += u0.y + u1.y;
            a2 += w0.x + w1.x; a3 += w0.y + w1.y;
        }
        for (; i < end; i += 4) {
            int s = csr[i];
            uint v = P2f8[(size_t)s * 16 + l];
            floatx2 u = f8lo(v), w2 = f8hi(v);
            a0 += u.x; a1 += u.y; a2 += w2.x; a3 += w2.y;
        }
        #pragma unroll
        for (int d = 16; d <= 32; d <<= 1) {
            a0 += __shfl_xor(a0, d, 64);
            a1 += __shfl_xor(a1, d, 64);
            a2 += __shfl_xor(a2, d, 64);
            a3 += __shfl_xor(a3, d, 64);
        }
        float inv = 1.0f / (float)max(end - beg, 1);
        uint2 qv = *(const uint2*)&Q2u[(size_t)node * 32 + l * 2];
        float2 q0 = bf2x(qv.x), q1 = bf2x(qv.y);
        float L0 = fmaf(a0, inv, q0.x);
        float L1 = fmaf(a1, inv, q0.y);
        float L2 = fmaf(a2, inv, q1.x);
        float L3 = fmaf(a3, inv, q1.y);
        float mx = fmaxf(fmaxf(L0, L1), fmaxf(L2, L3));
        #pragma unroll
        for (int d = 1; d <= 8; d <<= 1) mx = fmaxf(mx, __shfl_xor(mx, d, 64));
        float s = __expf(L0 - mx) + __expf(L1 - mx) + __expf(L2 - mx) + __expf(L3 - mx);
        #pragma unroll
        for (int d = 1; d <= 8; d <<= 1) s += __shfl_xor(s, d, 64);
        int cls = y[node];
        int srcl = (cls >> 2) & 15;
        float c0 = __shfl(L0, srcl, 64);
        float c1 = __shfl(L1, srcl, 64);
        float c2 = __shfl(L2, srcl, 64);
        float c3 = __shfl(L3, srcl, 64);
        int sel = cls & 3;
        float Lc = (sel == 0) ? c0 : (sel == 1) ? c1 : (sel == 2) ? c2 : c3;
        float logp = (Lc - mx) - __logf(s);
        int f = sflag;
        bool m;
        if (f == 0)      m = ((const unsigned char*)tmask)[node] != 0;
        else if (f == 1) m = ((const int*)tmask)[node] != 0;
        else             m = ((const float*)tmask)[node] != 0.f;
        if (m) { num = -logp; den = 1.f; }
    }
    __shared__ float2 wacc[16];
    if (lane == 0) wacc[wid] = make_float2(num, den);
    __syncthreads();
    if (threadIdx.x == 0) {
        float rx = 0.f, ry = 0.f;
        #pragma unroll
        for (int i = 0; i < 16; ++i) { rx += wacc[i].x; ry += wacc[i].y; }
        bpart[blockIdx.x] = make_float2(rx, ry);
    }
}

__global__ __launch_bounds__(1024) void finalize_kernel(const float2* __restrict__ bpart, int nb,
                                                        float* __restrict__ out) {
    int t = threadIdx.x;
    float sx = 0.f, sy = 0.f;
    for (int i = t; i < nb; i += 1024) { float2 v = bpart[i]; sx += v.x; sy += v.y; }
    #pragma unroll
    for (int d = 32; d; d >>= 1) { sx += __shfl_down(sx, d, 64); sy += __shfl_down(sy, d, 64); }
    __shared__ float2 wacc[16];
    if ((t & 63) == 0) wacc[t >> 6] = make_float2(sx, sy);
    __syncthreads();
    if (t == 0) {
        float nx = 0.f, ny = 0.f;
        #pragma unroll
        for (int i = 0; i < 16; ++i) { nx += wacc[i].x; ny += wacc[i].y; }
        out[0] = nx / fmaxf(ny, 1.f);
    }
}

extern "C" void kernel_launch(void* const* d_in, const int* in_sizes, int n_in,
                              void* d_out, int out_size, void* d_ws, size_t ws_size,
                              hipStream_t stream) {
    const float* x        = (const float*)d_in[0];
    const int*   edge_src = (const int*)d_in[1];
    const int*   edge_dst = (const int*)d_in[2];
    const int*   y        = (const int*)d_in[3];
    const void*  tmask    = (const void*)d_in[4];
    const float* W1l      = (const float*)d_in[5];
    const float* b1       = (const float*)d_in[6];
    const float* W1r      = (const float*)d_in[7];
    const float* W2l      = (const float*)d_in[8];
    const float* b2       = (const float*)d_in[9];
    const float* W2r      = (const float*)d_in[10];

    const int N = in_sizes[0] / DIN;
    const int E = in_sizes[1];
    const int nb_loss = (N + 15) / 16;
    const bool small_idx = (N <= 65535);
    const int nb = (N + 255) >> BSH;

    char* ws = (char*)d_ws;
    int* gflags = (int*)ws;              // [0..1]
    size_t off = 256;
    uint* bcounts = (uint*)(ws + off); off += al256(513 * 4);
    uint* bcursor = (uint*)(ws + off); off += al256(513 * 4);
    int* offsets  = (int*)(ws + off); off += al256(((size_t)N + 1) * 4);
    uint* pairs   = (uint*)(ws + off); off += al256((size_t)E * 4);
    void* csr     = (void*)(ws + off); off += al256((size_t)E * 4);  // u16 uses half
    int* counts   = (int*)(ws + off); off += al256((size_t)N * 4);   // fallback
    int* cursor   = (int*)(ws + off); off += al256((size_t)N * 4);   // fallback
    int* spart    = (int*)(ws + off); off += al256(64 * 4);          // fallback
    float2* bpart = (float2*)(ws + off); off += al256((size_t)nb_loss * 8);
    u16* Wp1      = (u16*)(ws + off); off += al256(32768 * 2);
    u16* Wp2      = (u16*)(ws + off); off += al256(16384 * 2);
    uint* P1f8    = (uint*)(ws + off); off += al256((size_t)N * 32 * 4);   // 6.4 MB (fp8 x 128)
    uint* h1u     = (uint*)(ws + off); off += al256((size_t)N * 64 * 4);   // 12.8 MB (bf16 x 128)
    uint* Q1u     = (uint*)(ws + off); off += al256((size_t)N * 64 * 4);   // 12.8 MB (bf16 x 128)
    // P2/Q2 overlay the dead Q1 region (Q1 last read by aggr1, before gemm2)
    uint* P2f8    = Q1u;                      // N*16 uints (fp8 x 64)
    uint* Q2u     = Q1u + (size_t)N * 16;     // N*32 uints (bf16 x 64)

    // zero control block: gflags + bcounts + bcursor (all within first 8 KB)
    hipMemsetAsync(ws, 0, 8192, stream);

    int gb32 = (N + 127) / 128;

    if (small_idx) {
        pack_detect_bhist_kernel<<<512, 256, 0, stream>>>(
            W1l, W1r, W2l, W2r, Wp1, Wp2, (const int*)tmask, N / 4, gflags,
            edge_dst, E, nb, bcounts);
        int pblocks = (E + P3CHUNK - 1) / P3CHUNK;
        partition_gemm1_kernel<<<pblocks + gb32, 256, 0, stream>>>(
            edge_src, edge_dst, E, nb, bcounts, bcursor, pairs, pblocks,
            x, Wp1, b1, P1f8, Q1u, N);
        emit_kernel<<<nb, 256, 0, stream>>>(pairs, bcounts, nb, E, N, (u16*)csr, offsets);
        int ab = (N + 3) / 4;
        aggr1_kernel<u16><<<ab, 256, 0, stream>>>(P1f8, Q1u, offsets, (const u16*)csr, h1u, N);
        gemm2_mfma<<<gb32, 256, 0, stream>>>(h1u, Wp2, b2, P2f8, Q2u, N);
        loss_kernel<u16><<<nb_loss, 1024, 0, stream>>>(
            P2f8, Q2u, offsets, (const u16*)csr, y, tmask, gflags, bpart, N);
    } else {
        pack_detect_bhist_kernel<<<256, 256, 0, stream>>>(
            W1l, W1r, W2l, W2r, Wp1, Wp2, (const int*)tmask, N / 4, gflags,
            edge_dst, E, nb, bcounts);
        hipMemsetAsync(counts, 0, (size_t)N * 4, stream);
        int eb4 = (E + 1023) / 1024;
        hist_kernel<<<eb4, 256, 0, stream>>>(edge_dst, E, counts);
        int sb = (N + 1023) / 1024;
        scan_partial_kernel<<<sb, 256, 0, stream>>>(counts, N, spart);
        scan_top_kernel<<<1, 64, 0, stream>>>(spart, sb, &offsets[N]);
        scan_final_kernel<<<sb, 256, 0, stream>>>(counts, N, spart, offsets, cursor);
        scatter_kernel<<<eb4, 256, 0, stream>>>(edge_src, edge_dst, E, cursor, (uint*)csr);
        partition_gemm1_kernel<<<gb32, 256, 0, stream>>>(
            edge_src, edge_dst, E, nb, bcounts, bcursor, pairs, 0,
            x, Wp1, b1, P1f8, Q1u, N);
        int ab = (N + 3) / 4;
        aggr1_kernel<uint><<<ab, 256, 0, stream>>>(P1f8, Q1u, offsets, (const uint*)csr, h1u, N);
        gemm2_mfma<<<gb32, 256, 0, stream>>>(h1u, Wp2, b2, P2f8, Q2u, N);
        loss_kernel<uint><<<nb_loss, 1024, 0, stream>>>(
            P2f8, Q2u, offsets, (const uint*)csr, y, tmask, gflags, bpart, N);
    }
    finalize_kernel<<<1, 1024, 0, stream>>>(bpart, nb_loss, (float*)d_out);
}

// Round 13
// 202.501 us; speedup vs baseline: 1.0612x; 1.0612x over previous
//
#include <hip/hip_runtime.h>
#include <hip/hip_bf16.h>

typedef unsigned int uint;
typedef unsigned short u16;

// Dims fixed by the problem
#define DIN 128
#define DHID 128
#define DOUT 64
#define BSH 8          // bucket = dst >> 8 (256 nodes per bucket)
#define P3CHUNK 4096   // edges per partition block
#define P4MAX 6144     // LDS staging cap per bucket in emit

static inline size_t al256(size_t x) { return (x + 255) & ~(size_t)255; }

typedef __attribute__((ext_vector_type(8))) short short8;
typedef __attribute__((ext_vector_type(4))) float floatx4;
typedef __attribute__((ext_vector_type(2))) float floatx2;
typedef __attribute__((ext_vector_type(4))) int intx4;   // clang vector for nontemporal builtins

// bf16 pair helpers (uint = two bf16, low bits = even feature)
__device__ inline float2 bf2x(uint v) {
    return make_float2(__uint_as_float(v << 16), __uint_as_float(v & 0xffff0000u));
}
__device__ inline uint packbf(float a, float b) {
    uint ua = __float_as_uint(a), ub = __float_as_uint(b);
    ua += 0x7fff + ((ua >> 16) & 1);   // RNE
    ub += 0x7fff + ((ub >> 16) & 1);
    return (ua >> 16) | (ub & 0xffff0000u);
}
__device__ inline u16 pb(float a) {
    uint u = __float_as_uint(a);
    u += 0x7fff + ((u >> 16) & 1);
    return (u16)(u >> 16);
}

// ---- fp8 e4m3 helpers (HW cvt if available, exact software fallback) ----
__device__ inline floatx2 f8lo(uint v) {
#if __has_builtin(__builtin_amdgcn_cvt_pk_f32_fp8)
    return __builtin_amdgcn_cvt_pk_f32_fp8((int)v, false);
#else
    uint b0 = v & 0xffu, b1 = (v >> 8) & 0xffu;
    floatx2 r;
    r.x = __uint_as_float(((b0 & 0x80u) << 24) | ((b0 & 0x7fu) << 20)) * 0x1p120f;
    r.y = __uint_as_float(((b1 & 0x80u) << 24) | ((b1 & 0x7fu) << 20)) * 0x1p120f;
    return r;
#endif
}
__device__ inline floatx2 f8hi(uint v) {
#if __has_builtin(__builtin_amdgcn_cvt_pk_f32_fp8)
    return __builtin_amdgcn_cvt_pk_f32_fp8((int)v, true);
#else
    uint b0 = (v >> 16) & 0xffu, b1 = (v >> 24) & 0xffu;
    floatx2 r;
    r.x = __uint_as_float(((b0 & 0x80u) << 24) | ((b0 & 0x7fu) << 20)) * 0x1p120f;
    r.y = __uint_as_float(((b1 & 0x80u) << 24) | ((b1 & 0x7fu) << 20)) * 0x1p120f;
    return r;
#endif
}
__device__ inline uint enc8(float f) {
    uint ub = __float_as_uint(f * 0x1p-120f);
    uint s = (ub >> 24) & 0x80u;
    uint mag = ub & 0x7fffffffu;
    mag += 0x7ffffu + ((mag >> 20) & 1u);
    uint r = mag >> 20;
    if (r > 0x7eu) r = 0x7eu;
    return r | s;
}
__device__ inline uint packf8x4(float a, float b, float c, float d) {
#if __has_builtin(__builtin_amdgcn_cvt_pk_fp8_f32)
    int p = __builtin_amdgcn_cvt_pk_fp8_f32(a, b, 0, false);
    p = __builtin_amdgcn_cvt_pk_fp8_f32(c, d, p, true);
    return (uint)p;
#else
    return enc8(a) | (enc8(b) << 8) | (enc8(c) << 16) | (enc8(d) << 24);
#endif
}

// ---- pack W (blocks 0..191) + mask detect (192..255) + bucket hist (256..511) ----
__global__ __launch_bounds__(256) void pack_detect_bhist_kernel(
    const float* __restrict__ W1l, const float* __restrict__ W1r,
    const float* __restrict__ W2l, const float* __restrict__ W2r,
    u16* __restrict__ Wp1, u16* __restrict__ Wp2,
    const int* __restrict__ tm, int n_int, int* __restrict__ gflags,
    const int* __restrict__ dst, int e, int nb, uint* __restrict__ bcounts) {
    __shared__ uint lh[512];
    int bx = blockIdx.x;
    if (bx < 192) {
        int id = bx * 256 + threadIdx.x;
        if (id < 32768) {
            int frag = id >> 9, el = id & 511;
            int lane = el >> 3, j = el & 7;
            int kc = frag >> 4, tn = frag & 15;
            int k = kc * 32 + (lane >> 4) * 8 + j;
            int ncol = tn * 16 + (lane & 15);
            float v = (ncol < 128) ? W1l[k * 128 + ncol] : W1r[k * 128 + ncol - 128];
            Wp1[id] = pb(v);
        } else if (id < 49152) {
            int id2 = id - 32768;
            int frag = id2 >> 9, el = id2 & 511;
            int lane = el >> 3, j = el & 7;
            int kc = frag >> 3, tn = frag & 7;
            int k = kc * 32 + (lane >> 4) * 8 + j;
            int ncol = tn * 16 + (lane & 15);
            float v = (ncol < 64) ? W2l[k * 64 + ncol] : W2r[k * 64 + ncol - 64];
            Wp2[id2] = pb(v);
        }
    } else if (bx < 256) {
        int i = (bx - 192) * 256 + threadIdx.x;
        bool hf = false, ho = false;
        for (; i < n_int; i += 64 * 256) {
            int v = tm[i];
            hf |= (v == 0x3F800000);
            ho |= (v != 0 && v != 1 && v != 0x3F800000);
        }
        if (__any(hf) && (threadIdx.x & 63) == 0) atomicOr(&gflags[0], 1);
        if (__any(ho) && (threadIdx.x & 63) == 0) atomicOr(&gflags[1], 1);
    } else {
        for (int i = threadIdx.x; i < 512; i += 256) lh[i] = 0;
        __syncthreads();
        int nquad = (e + 3) >> 2;
        for (int i = (bx - 256) * 256 + threadIdx.x; i < nquad; i += 256 * 256) {
            int base = i * 4;
            if (base + 4 <= e) {
                intx4 d = __builtin_nontemporal_load((const intx4*)(dst + base));
                atomicAdd(&lh[d.x >> BSH], 1u);
                atomicAdd(&lh[d.y >> BSH], 1u);
                atomicAdd(&lh[d.z >> BSH], 1u);
                atomicAdd(&lh[d.w >> BSH], 1u);
            } else {
                for (int k = base; k < e; ++k) atomicAdd(&lh[dst[k] >> BSH], 1u);
            }
        }
        __syncthreads();
        for (int i = threadIdx.x; i < nb; i += 256) {
            uint c = lh[i];
            if (c) atomicAdd(&bcounts[i], c);
        }
    }
}

// ---- fused: blocks [0, npart) = partition; blocks [npart, ...) = gemm1 MFMA ----
// gemm1: 16 rows/wave (acc[16] = 64 regs — R12: reverted from 32-row/wave whose
// 128 acc regs halved residency and made the latency-bound kernel 2x slower).
__global__ __launch_bounds__(256) void partition_gemm1_kernel(
    const int* __restrict__ src, const int* __restrict__ dst, int e, int nb,
    const uint* __restrict__ bcounts, uint* __restrict__ bcursor,
    uint* __restrict__ pairs, int npart,
    const float* __restrict__ X, const u16* __restrict__ Wp1,
    const float* __restrict__ b1,
    uint* __restrict__ P1f8, uint* __restrict__ Q1u, int n) {
    __shared__ uint sbuf[8320];   // 33,280 B, aliased by both paths
    int t = threadIdx.x;
    if (blockIdx.x < npart) {
        uint* lh    = sbuf;          // 512
        uint* lexcl = sbuf + 512;    // 512
        uint* lbase = sbuf + 1024;   // 512
        uint* lpos  = sbuf + 1536;   // 512
        uint* pws   = sbuf + 2048;   // 8
        uint* st    = sbuf + 2056;   // P3CHUNK (4096)
        int e0 = blockIdx.x * P3CHUNK;
        int ecnt = min(P3CHUNK, e - e0);
        for (int i = t; i < 512; i += 256) { lh[i] = 0; lpos[i] = 0; }
        __syncthreads();
        int nquad = (ecnt + 3) >> 2;
        for (int i = t; i < nquad; i += 256) {
            int b4 = i * 4;
            if (b4 + 4 <= ecnt) {
                intx4 d = *(const intx4*)(dst + e0 + b4);
                atomicAdd(&lh[d.x >> BSH], 1u);
                atomicAdd(&lh[d.y >> BSH], 1u);
                atomicAdd(&lh[d.z >> BSH], 1u);
                atomicAdd(&lh[d.w >> BSH], 1u);
            } else {
                for (int k = b4; k < ecnt; ++k) atomicAdd(&lh[dst[e0 + k] >> BSH], 1u);
            }
        }
        __syncthreads();
        {
            uint v0 = lh[2 * t], v1 = lh[2 * t + 1];
            uint s = v0 + v1;
            int lane = t & 63, wv = t >> 6;
            uint incl = s;
            #pragma unroll
            for (int d = 1; d < 64; d <<= 1) {
                uint u = (uint)__shfl_up((int)incl, d, 64);
                if (lane >= d) incl += u;
            }
            if (lane == 63) pws[wv] = incl;
            __syncthreads();
            uint woff = 0;
            #pragma unroll
            for (int i = 0; i < 4; ++i) if (i < wv) woff += pws[i];
            uint excl = woff + incl - s;
            lexcl[2 * t] = excl;
            lexcl[2 * t + 1] = excl + v0;
        }
        __syncthreads();
        {
            uint v0 = (2 * t < nb) ? bcounts[2 * t] : 0u;
            uint v1 = (2 * t + 1 < nb) ? bcounts[2 * t + 1] : 0u;
            uint s = v0 + v1;
            int lane = t & 63, wv = t >> 6;
            uint incl = s;
            #pragma unroll
            for (int d = 1; d < 64; d <<= 1) {
                uint u = (uint)__shfl_up((int)incl, d, 64);
                if (lane >= d) incl += u;
            }
            if (lane == 63) pws[wv] = incl;
            __syncthreads();
            uint woff = 0;
            #pragma unroll
            for (int i = 0; i < 4; ++i) if (i < wv) woff += pws[i];
            uint excl = woff + incl - s;
            if (2 * t < nb) lbase[2 * t] = excl;
            if (2 * t + 1 < nb) lbase[2 * t + 1] = excl + v0;
        }
        __syncthreads();
        for (int b = t; b < nb; b += 256) {
            uint c = lh[b];
            if (c) lbase[b] += atomicAdd(&bcursor[b], c);
        }
        __syncthreads();
        for (int i = t; i < nquad; i += 256) {
            int b4 = i * 4;
            if (b4 + 4 <= ecnt) {
                intx4 dd = *(const intx4*)(dst + e0 + b4);
                intx4 ss = *(const intx4*)(src + e0 + b4);
                #pragma unroll
                for (int k = 0; k < 4; ++k) {
                    int d = (k == 0) ? dd.x : (k == 1) ? dd.y : (k == 2) ? dd.z : dd.w;
                    int s = (k == 0) ? ss.x : (k == 1) ? ss.y : (k == 2) ? ss.z : ss.w;
                    int b = d >> BSH;
                    uint slot = lexcl[b] + atomicAdd(&lpos[b], 1u);
                    st[slot] = ((uint)(d & ((1 << BSH) - 1)) << 16) | (uint)s;
                }
            } else {
                for (int k = b4; k < ecnt; ++k) {
                    int d = dst[e0 + k];
                    int s = src[e0 + k];
                    int b = d >> BSH;
                    uint slot = lexcl[b] + atomicAdd(&lpos[b], 1u);
                    st[slot] = ((uint)(d & ((1 << BSH) - 1)) << 16) | (uint)s;
                }
            }
        }
        __syncthreads();
        int wv = t >> 6, lane = t & 63;
        for (int b = wv; b < nb; b += 4) {
            uint c = lh[b];
            uint lsrc = lexcl[b], gdst = lbase[b];
            for (uint k = lane; k < c; k += 64)
                pairs[gdst + k] = st[lsrc + k];
        }
        return;
    }
    // ---------- gemm1: 16 rows/wave, 64 rows/block ----------
    u16* ep = (u16*)sbuf;   // [4][16][260]
    int bid = blockIdx.x - npart;
    int w = t >> 6, lane = t & 63;
    int q = lane >> 4, c = lane & 15;
    int m0 = bid * 64 + w * 16;
    int me = min(m0 + c, n - 1);
    const float* xrow = X + (size_t)me * 128 + q * 8;
    const u16* wbase = Wp1 + lane * 8;

    floatx4 acc[16];
    #pragma unroll
    for (int i = 0; i < 16; ++i) acc[i] = (floatx4){0.f, 0.f, 0.f, 0.f};

    #pragma unroll
    for (int kc = 0; kc < 4; ++kc) {
        float4 x0 = *(const float4*)(xrow + kc * 32);
        float4 x1 = *(const float4*)(xrow + kc * 32 + 4);
        union { short8 s; uint4 u; } a;
        a.u.x = packbf(x0.x, x0.y); a.u.y = packbf(x0.z, x0.w);
        a.u.z = packbf(x1.x, x1.y); a.u.w = packbf(x1.z, x1.w);
        #pragma unroll
        for (int tn = 0; tn < 16; ++tn) {
            union { short8 s; uint4 u; } b;
            b.u = *(const uint4*)(wbase + (kc * 16 + tn) * 512);
            acc[tn] = __builtin_amdgcn_mfma_f32_16x16x32_bf16(a.s, b.s, acc[tn], 0, 0, 0);
        }
    }

    #pragma unroll
    for (int tn = 0; tn < 16; ++tn) {
        int col = tn * 16 + c;
        float badd = (tn >= 8) ? b1[col - 128] : 0.f;
        #pragma unroll
        for (int i = 0; i < 4; ++i)
            ep[((size_t)w * 16 + (q * 4 + i)) * 260 + col] = pb(acc[tn][i] + badd);
    }
    for (int r = 0; r < 16; ++r) {
        int grow = m0 + r;
        if (grow >= n) break;
        uint2 v = *(const uint2*)&ep[((size_t)w * 16 + r) * 260 + lane * 4];
        if (lane < 32) {
            float2 e0 = bf2x(v.x), e1 = bf2x(v.y);
            P1f8[(size_t)grow * 32 + lane] = packf8x4(e0.x, e0.y, e1.x, e1.y);
        } else {
            *(uint2*)&Q1u[(size_t)grow * 64 + 2 * (lane - 32)] = v;
        }
    }
}

// emit: per-bucket local sort -> dense csr segment + offsets (computes bucket bases locally)
__global__ __launch_bounds__(256) void emit_kernel(const uint* __restrict__ pairs,
                                                   const uint* __restrict__ bcounts, int nb,
                                                   int e, int n,
                                                   u16* __restrict__ csr, int* __restrict__ offsets) {
    __shared__ uint cnt[256], lex[256], gb[512], pws[8];
    __shared__ u16 ob[P4MAX];
    int b = blockIdx.x, t = threadIdx.x;
    {
        uint v0 = (2 * t < nb) ? bcounts[2 * t] : 0u;
        uint v1 = (2 * t + 1 < nb) ? bcounts[2 * t + 1] : 0u;
        uint s = v0 + v1;
        int lane = t & 63, wv = t >> 6;
        uint incl = s;
        #pragma unroll
        for (int d = 1; d < 64; d <<= 1) {
            uint u = (uint)__shfl_up((int)incl, d, 64);
            if (lane >= d) incl += u;
        }
        if (lane == 63) pws[wv] = incl;
        __syncthreads();
        uint woff = 0;
        #pragma unroll
        for (int i = 0; i < 4; ++i) if (i < wv) woff += pws[i];
        uint excl = woff + incl - s;
        if (2 * t < nb) gb[2 * t] = excl;
        if (2 * t + 1 < nb) gb[2 * t + 1] = excl + v0;
    }
    __syncthreads();
    uint seg0 = gb[b];
    int len = (int)bcounts[b];
    int n0 = b << BSH;
    if (b == 0 && t == 0) offsets[n] = e;
    cnt[t] = 0;
    __syncthreads();
    for (int i = t; i < len; i += 256)
        atomicAdd(&cnt[pairs[seg0 + i] >> 16], 1u);
    __syncthreads();
    uint v = cnt[t];
    int lane = t & 63, wv = t >> 6;
    uint incl = v;
    #pragma unroll
    for (int d = 1; d < 64; d <<= 1) {
        uint u = (uint)__shfl_up((int)incl, d, 64);
        if (lane >= d) incl += u;
    }
    if (lane == 63) pws[wv] = incl;
    __syncthreads();
    uint woff = 0;
    #pragma unroll
    for (int i = 0; i < 4; ++i) if (i < wv) woff += pws[i];
    uint excl = woff + incl - v;
    lex[t] = excl;
    if (n0 + t < n) offsets[n0 + t] = (int)(seg0 + excl);
    __syncthreads();
    cnt[t] = 0;
    __syncthreads();
    for (int i = t; i < len; i += 256) {
        uint p = pairs[seg0 + i];
        uint loc = p >> 16;
        uint slot = lex[loc] + atomicAdd(&cnt[loc], 1u);
        if (slot < P4MAX) ob[slot] = (u16)(p & 0xffffu);
        else csr[seg0 + slot] = (u16)(p & 0xffffu);
    }
    __syncthreads();
    int lim = min(len, P4MAX);
    for (int i = t; i < lim; i += 256) csr[seg0 + i] = ob[i];
}

// ================= fallback CSR build for N > 65535 (old path) =================
__global__ __launch_bounds__(256) void hist_kernel(const int* __restrict__ dst, int e,
                                                   int* __restrict__ counts) {
    int base = (blockIdx.x * 256 + threadIdx.x) * 4;
    if (base + 4 <= e) {
        intx4 d = __builtin_nontemporal_load((const intx4*)(dst + base));
        atomicAdd(&counts[d.x], 1);
        atomicAdd(&counts[d.y], 1);
        atomicAdd(&counts[d.z], 1);
        atomicAdd(&counts[d.w], 1);
    } else {
        for (int i = base; i < e; ++i) atomicAdd(&counts[dst[i]], 1);
    }
}

__global__ __launch_bounds__(256) void scan_partial_kernel(const int* __restrict__ counts, int n,
                                                           int* __restrict__ partials) {
    int t = threadIdx.x;
    int base = blockIdx.x * 1024 + t * 4;
    int s = 0;
    if (base + 3 < n) {
        int4 v = *(const int4*)&counts[base];
        s = v.x + v.y + v.z + v.w;
    } else {
        for (int i = 0; i < 4; ++i) if (base + i < n) s += counts[base + i];
    }
    #pragma unroll
    for (int d = 32; d; d >>= 1) s += __shfl_down(s, d, 64);
    __shared__ int wsum[4];
    if ((t & 63) == 0) wsum[t >> 6] = s;
    __syncthreads();
    if (t == 0) partials[blockIdx.x] = wsum[0] + wsum[1] + wsum[2] + wsum[3];
}

__global__ void scan_top_kernel(int* __restrict__ partials, int nparts, int* __restrict__ total_out) {
    int lane = threadIdx.x;
    int v = (lane < nparts) ? partials[lane] : 0;
    int incl = v;
    #pragma unroll
    for (int d = 1; d < 64; d <<= 1) {
        int u = __shfl_up(incl, d, 64);
        if (lane >= d) incl += u;
    }
    if (lane < nparts) partials[lane] = incl - v;
    if (lane == 63) *total_out = incl;
}

__global__ __launch_bounds__(256) void scan_final_kernel(const int* __restrict__ counts, int n,
                                                         const int* __restrict__ partials,
                                                         int* __restrict__ offsets,
                                                         int* __restrict__ cursor) {
    int t = threadIdx.x;
    int base = blockIdx.x * 1024 + t * 4;
    int v0 = 0, v1 = 0, v2 = 0, v3 = 0;
    if (base + 3 < n) {
        int4 q = *(const int4*)&counts[base];
        v0 = q.x; v1 = q.y; v2 = q.z; v3 = q.w;
    } else {
        if (base + 0 < n) v0 = counts[base + 0];
        if (base + 1 < n) v1 = counts[base + 1];
        if (base + 2 < n) v2 = counts[base + 2];
        if (base + 3 < n) v3 = counts[base + 3];
    }
    int s = v0 + v1 + v2 + v3;
    int lane = t & 63, wid = t >> 6;
    int incl = s;
    #pragma unroll
    for (int d = 1; d < 64; d <<= 1) {
        int u = __shfl_up(incl, d, 64);
        if (lane >= d) incl += u;
    }
    __shared__ int wsum[4];
    if (lane == 63) wsum[wid] = incl;
    __syncthreads();
    int woff = 0;
    #pragma unroll
    for (int i = 0; i < 4; ++i) if (i < wid) woff += wsum[i];
    int run = partials[blockIdx.x] + woff + incl - s;
    if (base + 0 < n) { offsets[base + 0] = run; cursor[base + 0] = run; run += v0; }
    if (base + 1 < n) { offsets[base + 1] = run; cursor[base + 1] = run; run += v1; }
    if (base + 2 < n) { offsets[base + 2] = run; cursor[base + 2] = run; run += v2; }
    if (base + 3 < n) { offsets[base + 3] = run; cursor[base + 3] = run; run += v3; }
}

__global__ __launch_bounds__(256) void scatter_kernel(const int* __restrict__ src,
                                                      const int* __restrict__ dst, int e,
                                                      int* __restrict__ cursor,
                                                      uint* __restrict__ csr_src) {
    int base = (blockIdx.x * 256 + threadIdx.x) * 4;
    if (base + 4 <= e) {
        intx4 s = __builtin_nontemporal_load((const intx4*)(src + base));
        intx4 d = __builtin_nontemporal_load((const intx4*)(dst + base));
        int p0 = atomicAdd(&cursor[d.x], 1);
        int p1 = atomicAdd(&cursor[d.y], 1);
        int p2 = atomicAdd(&cursor[d.z], 1);
        int p3 = atomicAdd(&cursor[d.w], 1);
        csr_src[p0] = (uint)s.x;
        csr_src[p1] = (uint)s.y;
        csr_src[p2] = (uint)s.z;
        csr_src[p3] = (uint)s.w;
    } else {
        for (int i = base; i < e; ++i) {
            int p = atomicAdd(&cursor[dst[i]], 1);
            csr_src[p] = (uint)src[i];
        }
    }
}

// ---------------- aggr1: h1 = bf16(relu(mean(P1) + Q1)), half-wave per edge ----------------
template <typename IT>
__global__ __launch_bounds__(256) void aggr1_kernel(
    const uint* __restrict__ P1f8, const uint* __restrict__ Q1u,
    const int* __restrict__ offsets, const IT* __restrict__ csr,
    uint* __restrict__ h1u, int n) {
    int node = (int)((blockIdx.x * (size_t)blockDim.x + threadIdx.x) >> 6);
    int lane = threadIdx.x & 63;
    int l = lane & 31, hw = lane >> 5;
    if (node >= n) return;
    int beg = offsets[node], end = offsets[node + 1];
    float a0 = 0.f, a1 = 0.f, a2 = 0.f, a3 = 0.f;
    int i = beg + hw;
    for (; i + 6 < end; i += 8) {
        int s0 = csr[i], s1 = csr[i + 2], s2 = csr[i + 4], s3 = csr[i + 6];
        uint v0 = P1f8[(size_t)s0 * 32 + l];
        uint v1 = P1f8[(size_t)s1 * 32 + l];
        uint v2 = P1f8[(size_t)s2 * 32 + l];
        uint v3 = P1f8[(size_t)s3 * 32 + l];
        floatx2 u0 = f8lo(v0), w0 = f8hi(v0);
        floatx2 u1 = f8lo(v1), w1 = f8hi(v1);
        floatx2 u2 = f8lo(v2), w2 = f8hi(v2);
        floatx2 u3 = f8lo(v3), w3 = f8hi(v3);
        a0 += (u0.x + u1.x) + (u2.x + u3.x);
        a1 += (u0.y + u1.y) + (u2.y + u3.y);
        a2 += (w0.x + w1.x) + (w2.x + w3.x);
        a3 += (w0.y + w1.y) + (w2.y + w3.y);
    }
    for (; i < end; i += 2) {
        int s = csr[i];
        uint v = P1f8[(size_t)s * 32 + l];
        floatx2 u = f8lo(v), w2 = f8hi(v);
        a0 += u.x; a1 += u.y; a2 += w2.x; a3 += w2.y;
    }
    a0 += __shfl_xor(a0, 32, 64);
    a1 += __shfl_xor(a1, 32, 64);
    a2 += __shfl_xor(a2, 32, 64);
    a3 += __shfl_xor(a3, 32, 64);
    if (hw == 0) {
        float inv = 1.0f / (float)max(end - beg, 1);
        uint2 qv = *(const uint2*)&Q1u[(size_t)node * 64 + l * 2];
        float2 q0 = bf2x(qv.x), q1 = bf2x(qv.y);
        float r0 = fmaxf(fmaf(a0, inv, q0.x), 0.f);
        float r1 = fmaxf(fmaf(a1, inv, q0.y), 0.f);
        float r2 = fmaxf(fmaf(a2, inv, q1.x), 0.f);
        float r3 = fmaxf(fmaf(a3, inv, q1.y), 0.f);
        uint2 o;
        o.x = packbf(r0, r1);
        o.y = packbf(r2, r3);
        *(uint2*)&h1u[(size_t)node * 64 + l * 2] = o;
    }
}

// ---------------- gemm2 (MFMA): 32 rows/wave; P2 = fp8(h1@W2l), Q2 = bf16(h1@W2r + b2) ----------------
__global__ __launch_bounds__(256) void gemm2_mfma(
    const uint* __restrict__ H1u, const u16* __restrict__ Wp2,
    const float* __restrict__ b2,
    uint* __restrict__ P2f8, uint* __restrict__ Q2u, int n) {
    __shared__ u16 ep[4][16][132];
    int t = threadIdx.x;
    int w = t >> 6, lane = t & 63;
    int q = lane >> 4, c = lane & 15;
    int m0 = blockIdx.x * 128 + w * 32;
    int meA = min(m0 + c, n - 1);
    int meB = min(m0 + 16 + c, n - 1);
    const u16* hrowA = (const u16*)H1u + (size_t)meA * 128 + q * 8;
    const u16* hrowB = (const u16*)H1u + (size_t)meB * 128 + q * 8;
    const u16* wbase = Wp2 + lane * 8;

    floatx4 acc[2][8];
    #pragma unroll
    for (int h = 0; h < 2; ++h)
        #pragma unroll
        for (int i = 0; i < 8; ++i) acc[h][i] = (floatx4){0.f, 0.f, 0.f, 0.f};

    #pragma unroll
    for (int kc = 0; kc < 4; ++kc) {
        union { short8 s; uint4 u; } a0, a1;
        a0.u = *(const uint4*)(hrowA + kc * 32);
        a1.u = *(const uint4*)(hrowB + kc * 32);
        #pragma unroll
        for (int tn = 0; tn < 8; ++tn) {
            union { short8 s; uint4 u; } b;
            b.u = *(const uint4*)(wbase + (kc * 8 + tn) * 512);
            acc[0][tn] = __builtin_amdgcn_mfma_f32_16x16x32_bf16(a0.s, b.s, acc[0][tn], 0, 0, 0);
            acc[1][tn] = __builtin_amdgcn_mfma_f32_16x16x32_bf16(a1.s, b.s, acc[1][tn], 0, 0, 0);
        }
    }

    #pragma unroll
    for (int h = 0; h < 2; ++h) {
        #pragma unroll
        for (int tn = 0; tn < 8; ++tn) {
            int col = tn * 16 + c;
            float badd = (tn >= 4) ? b2[col - 64] : 0.f;
            #pragma unroll
            for (int i = 0; i < 4; ++i)
                ep[w][q * 4 + i][col] = pb(acc[h][tn][i] + badd);
        }
        int r0 = m0 + h * 16;
        for (int r = 0; r < 16; ++r) {
            int grow = r0 + r;
            if (grow >= n) continue;
            if (lane < 16) {
                uint2 v = *(const uint2*)&ep[w][r][lane * 4];
                float2 e0 = bf2x(v.x), e1 = bf2x(v.y);
                P2f8[(size_t)grow * 16 + lane] = packf8x4(e0.x, e0.y, e1.x, e1.y);
            } else if (lane < 48) {
                uint v = *(const uint*)&ep[w][r][64 + (lane - 16) * 2];
                Q2u[(size_t)grow * 32 + (lane - 16)] = v;
            }
        }
    }
}

// ---------------- loss: logits = mean(P2) + Q2 ; log_softmax ; masked NLL ----------------
// Per-block float2 partial (NO global atomics / fences — R8's fused finalize cost ~100 µs).
template <typename IT>
__global__ __launch_bounds__(1024) void loss_kernel(
    const uint* __restrict__ P2f8, const uint* __restrict__ Q2u,
    const int* __restrict__ offsets, const IT* __restrict__ csr,
    const int* __restrict__ y, const void* __restrict__ tmask,
    const int* __restrict__ gflags, float2* __restrict__ bpart, int n) {
    __shared__ int sflag;
    if (threadIdx.x == 0) sflag = gflags[0] ? 2 : (gflags[1] ? 0 : 1);
    int wid = threadIdx.x >> 6;
    int node = blockIdx.x * 16 + wid;
    int lane = threadIdx.x & 63;
    int l = lane & 15, qw = lane >> 4;
    __syncthreads();
    float num = 0.f, den = 0.f;
    if (node < n) {
        int beg = offsets[node], end = offsets[node + 1];
        float a0 = 0.f, a1 = 0.f, a2 = 0.f, a3 = 0.f;
        int i = beg + qw;
        for (; i + 4 < end; i += 8) {
            int s0 = csr[i], s1 = csr[i + 4];
            uint v0 = P2f8[(size_t)s0 * 16 + l];
            uint v1 = P2f8[(size_t)s1 * 16 + l];
            floatx2 u0 = f8lo(v0), w0 = f8hi(v0);
            floatx2 u1 = f8lo(v1), w1 = f8hi(v1);
            a0 += u0.x + u1.x; a1 += u0.y + u1.y;
            a2 += w0.x + w1.x; a3 += w0.y + w1.y;
        }
        for (; i < end; i += 4) {
            int s = csr[i];
            uint v = P2f8[(size_t)s * 16 + l];
            floatx2 u = f8lo(v), w2 = f8hi(v);
            a0 += u.x; a1 += u.y; a2 += w2.x; a3 += w2.y;
        }
        #pragma unroll
        for (int d = 16; d <= 32; d <<= 1) {
            a0 += __shfl_xor(a0, d, 64);
            a1 += __shfl_xor(a1, d, 64);
            a2 += __shfl_xor(a2, d, 64);
            a3 += __shfl_xor(a3, d, 64);
        }
        float inv = 1.0f / (float)max(end - beg, 1);
        uint2 qv = *(const uint2*)&Q2u[(size_t)node * 32 + l * 2];
        float2 q0 = bf2x(qv.x), q1 = bf2x(qv.y);
        float L0 = fmaf(a0, inv, q0.x);
        float L1 = fmaf(a1, inv, q0.y);
        float L2 = fmaf(a2, inv, q1.x);
        float L3 = fmaf(a3, inv, q1.y);
        float mx = fmaxf(fmaxf(L0, L1), fmaxf(L2, L3));
        #pragma unroll
        for (int d = 1; d <= 8; d <<= 1) mx = fmaxf(mx, __shfl_xor(mx, d, 64));
        float s = __expf(L0 - mx) + __expf(L1 - mx) + __expf(L2 - mx) + __expf(L3 - mx);
        #pragma unroll
        for (int d = 1; d <= 8; d <<= 1) s += __shfl_xor(s, d, 64);
        int cls = y[node];
        int srcl = (cls >> 2) & 15;
        float c0 = __shfl(L0, srcl, 64);
        float c1 = __shfl(L1, srcl, 64);
        float c2 = __shfl(L2, srcl, 64);
        float c3 = __shfl(L3, srcl, 64);
        int sel = cls & 3;
        float Lc = (sel == 0) ? c0 : (sel == 1) ? c1 : (sel == 2) ? c2 : c3;
        float logp = (Lc - mx) - __logf(s);
        int f = sflag;
        bool m;
        if (f == 0)      m = ((const unsigned char*)tmask)[node] != 0;
        else if (f == 1) m = ((const int*)tmask)[node] != 0;
        else             m = ((const float*)tmask)[node] != 0.f;
        if (m) { num = -logp; den = 1.f; }
    }
    __shared__ float2 wacc[16];
    if (lane == 0) wacc[wid] = make_float2(num, den);
    __syncthreads();
    if (threadIdx.x == 0) {
        float rx = 0.f, ry = 0.f;
        #pragma unroll
        for (int i = 0; i < 16; ++i) { rx += wacc[i].x; ry += wacc[i].y; }
        bpart[blockIdx.x] = make_float2(rx, ry);
    }
}

__global__ __launch_bounds__(1024) void finalize_kernel(const float2* __restrict__ bpart, int nb,
                                                        float* __restrict__ out) {
    int t = threadIdx.x;
    float sx = 0.f, sy = 0.f;
    for (int i = t; i < nb; i += 1024) { float2 v = bpart[i]; sx += v.x; sy += v.y; }
    #pragma unroll
    for (int d = 32; d; d >>= 1) { sx += __shfl_down(sx, d, 64); sy += __shfl_down(sy, d, 64); }
    __shared__ float2 wacc[16];
    if ((t & 63) == 0) wacc[t >> 6] = make_float2(sx, sy);
    __syncthreads();
    if (t == 0) {
        float nx = 0.f, ny = 0.f;
        #pragma unroll
        for (int i = 0; i < 16; ++i) { nx += wacc[i].x; ny += wacc[i].y; }
        out[0] = nx / fmaxf(ny, 1.f);
    }
}

extern "C" void kernel_launch(void* const* d_in, const int* in_sizes, int n_in,
                              void* d_out, int out_size, void* d_ws, size_t ws_size,
                              hipStream_t stream) {
    const float* x        = (const float*)d_in[0];
    const int*   edge_src = (const int*)d_in[1];
    const int*   edge_dst = (const int*)d_in[2];
    const int*   y        = (const int*)d_in[3];
    const void*  tmask    = (const void*)d_in[4];
    const float* W1l      = (const float*)d_in[5];
    const float* b1       = (const float*)d_in[6];
    const float* W1r      = (const float*)d_in[7];
    const float* W2l      = (const float*)d_in[8];
    const float* b2       = (const float*)d_in[9];
    const float* W2r      = (const float*)d_in[10];

    const int N = in_sizes[0] / DIN;
    const int E = in_sizes[1];
    const int nb_loss = (N + 15) / 16;
    const bool small_idx = (N <= 65535);
    const int nb = (N + 255) >> BSH;

    char* ws = (char*)d_ws;
    int* gflags = (int*)ws;              // [0..1]
    size_t off = 256;
    uint* bcounts = (uint*)(ws + off); off += al256(513 * 4);
    uint* bcursor = (uint*)(ws + off); off += al256(513 * 4);
    int* offsets  = (int*)(ws + off); off += al256(((size_t)N + 1) * 4);
    uint* pairs   = (uint*)(ws + off); off += al256((size_t)E * 4);
    void* csr     = (void*)(ws + off); off += al256((size_t)E * 4);  // u16 uses half
    int* counts   = (int*)(ws + off); off += al256((size_t)N * 4);   // fallback
    int* cursor   = (int*)(ws + off); off += al256((size_t)N * 4);   // fallback
    int* spart    = (int*)(ws + off); off += al256(64 * 4);          // fallback
    float2* bpart = (float2*)(ws + off); off += al256((size_t)nb_loss * 8);
    u16* Wp1      = (u16*)(ws + off); off += al256(32768 * 2);
    u16* Wp2      = (u16*)(ws + off); off += al256(16384 * 2);
    uint* P1f8    = (uint*)(ws + off); off += al256((size_t)N * 32 * 4);   // 6.4 MB (fp8 x 128)
    uint* h1u     = (uint*)(ws + off); off += al256((size_t)N * 64 * 4);   // 12.8 MB (bf16 x 128)
    uint* Q1u     = (uint*)(ws + off); off += al256((size_t)N * 64 * 4);   // 12.8 MB (bf16 x 128)
    // P2/Q2 overlay the dead Q1 region (Q1 last read by aggr1, before gemm2)
    uint* P2f8    = Q1u;                      // N*16 uints (fp8 x 64)
    uint* Q2u     = Q1u + (size_t)N * 16;     // N*32 uints (bf16 x 64)

    // zero control block: gflags + bcounts + bcursor (all within first 8 KB)
    hipMemsetAsync(ws, 0, 8192, stream);

    int gb16 = (N + 63) / 64;     // gemm1: 64 rows/block
    int gb32 = (N + 127) / 128;   // gemm2: 128 rows/block

    if (small_idx) {
        pack_detect_bhist_kernel<<<512, 256, 0, stream>>>(
            W1l, W1r, W2l, W2r, Wp1, Wp2, (const int*)tmask, N / 4, gflags,
            edge_dst, E, nb, bcounts);
        int pblocks = (E + P3CHUNK - 1) / P3CHUNK;
        partition_gemm1_kernel<<<pblocks + gb16, 256, 0, stream>>>(
            edge_src, edge_dst, E, nb, bcounts, bcursor, pairs, pblocks,
            x, Wp1, b1, P1f8, Q1u, N);
        emit_kernel<<<nb, 256, 0, stream>>>(pairs, bcounts, nb, E, N, (u16*)csr, offsets);
        int ab = (N + 3) / 4;
        aggr1_kernel<u16><<<ab, 256, 0, stream>>>(P1f8, Q1u, offsets, (const u16*)csr, h1u, N);
        gemm2_mfma<<<gb32, 256, 0, stream>>>(h1u, Wp2, b2, P2f8, Q2u, N);
        loss_kernel<u16><<<nb_loss, 1024, 0, stream>>>(
            P2f8, Q2u, offsets, (const u16*)csr, y, tmask, gflags, bpart, N);
    } else {
        pack_detect_bhist_kernel<<<256, 256, 0, stream>>>(
            W1l, W1r, W2l, W2r, Wp1, Wp2, (const int*)tmask, N / 4, gflags,
            edge_dst, E, nb, bcounts);
        hipMemsetAsync(counts, 0, (size_t)N * 4, stream);
        int eb4 = (E + 1023) / 1024;
        hist_kernel<<<eb4, 256, 0, stream>>>(edge_dst, E, counts);
        int sb = (N + 1023) / 1024;
        scan_partial_kernel<<<sb, 256, 0, stream>>>(counts, N, spart);
        scan_top_kernel<<<1, 64, 0, stream>>>(spart, sb, &offsets[N]);
        scan_final_kernel<<<sb, 256, 0, stream>>>(counts, N, spart, offsets, cursor);
        scatter_kernel<<<eb4, 256, 0, stream>>>(edge_src, edge_dst, E, cursor, (uint*)csr);
        partition_gemm1_kernel<<<gb16, 256, 0, stream>>>(
            edge_src, edge_dst, E, nb, bcounts, bcursor, pairs, 0,
            x, Wp1, b1, P1f8, Q1u, N);
        int ab = (N + 3) / 4;
        aggr1_kernel<uint><<<ab, 256, 0, stream>>>(P1f8, Q1u, offsets, (const uint*)csr, h1u, N);
        gemm2_mfma<<<gb32, 256, 0, stream>>>(h1u, Wp2, b2, P2f8, Q2u, N);
        loss_kernel<uint><<<nb_loss, 1024, 0, stream>>>(
            P2f8, Q2u, offsets, (const uint*)csr, y, tmask, gflags, bpart, N);
    }
    finalize_kernel<<<1, 1024, 0, stream>>>(bpart, nb_loss, (float*)d_out);
}